// Round 10
// baseline (1262.553 us; speedup 1.0000x reference)
//
#include <hip/hip_runtime.h>
#include <hip/hip_fp16.h>
#include <stdint.h>

// Problem constants (fixed by reference)
constexpr int N    = 100000;
constexpr int D    = 256;
constexpr int E    = 1600000;
constexpr int S    = 512;
constexpr int EMAX = 8;
constexpr int H    = 256;
constexpr int G4   = 4 * H;           // 1024 gate rows
constexpr int NB   = (N + 255) / 256; // 391 scan blocks

typedef _Float16 h2_t __attribute__((ext_vector_type(2)));
typedef __attribute__((ext_vector_type(8))) short short8;
typedef __attribute__((ext_vector_type(4))) float f32x4;

static __device__ __forceinline__ float fdot2f(uint32_t a, uint32_t b, float c) {
#if __has_builtin(__builtin_amdgcn_fdot2)
    return __builtin_amdgcn_fdot2(__builtin_bit_cast(h2_t, a), __builtin_bit_cast(h2_t, b), c, false);
#else
    __half2 ha = __builtin_bit_cast(__half2, a), hb = __builtin_bit_cast(__half2, b);
    float2 fa = __half22float2(ha), fb = __half22float2(hb);
    return c + fa.x * fb.x + fa.y * fb.y;
#endif
}

static __device__ __forceinline__ uint32_t bf16rne(float f) {
    uint32_t u = __builtin_bit_cast(uint32_t, f);
    return (u + 0x7FFFu + ((u >> 16) & 1u)) >> 16;
}
static __device__ __forceinline__ uint32_t pk2(float a, float b) {
    return bf16rne(a) | (bf16rne(b) << 16);
}
static __device__ __forceinline__ float bf2f(uint32_t hi16) {
    return __builtin_bit_cast(float, hi16 << 16);
}
static __device__ __forceinline__ float sigm(float x) { return 1.f / (1.f + __expf(-x)); }
static __device__ __forceinline__ float tanhfast(float x) {
    float e = __expf(-2.f * x);
    return 2.f / (1.f + e) - 1.f;
}

// ---------------- degree / norm ----------------
__global__ void k_deg(const int* __restrict__ dst, int* __restrict__ deg) {
    int e = blockIdx.x * 256 + threadIdx.x;
    if (e < E) atomicAdd(&deg[dst[e]], 1);
}

__global__ void k_dis(const int* __restrict__ deg, float* __restrict__ dis) {
    int n = blockIdx.x * 256 + threadIdx.x;
    if (n < N) {
        int d = deg[n];
        dis[n] = (d > 0) ? (1.0f / sqrtf((float)d)) : 0.0f;
    }
}

// ---------------- CSR build (scan over deg) ----------------
__global__ void k_scan1(const int* __restrict__ deg, int* __restrict__ bsum) {
    __shared__ int s[256];
    int i = blockIdx.x * 256 + threadIdx.x;
    s[threadIdx.x] = (i < N) ? deg[i] : 0;
    __syncthreads();
    for (int off = 128; off > 0; off >>= 1) {
        if (threadIdx.x < off) s[threadIdx.x] += s[threadIdx.x + off];
        __syncthreads();
    }
    if (threadIdx.x == 0) bsum[blockIdx.x] = s[0];
}

__global__ void k_scan2(const int* __restrict__ bsum, int* __restrict__ boff, int* __restrict__ row_ptr) {
    __shared__ int s[512];
    int t = threadIdx.x;
    int v = (t < NB) ? bsum[t] : 0;
    s[t] = v;
    __syncthreads();
    for (int off = 1; off < 512; off <<= 1) {
        int u = (t >= off) ? s[t - off] : 0;
        __syncthreads();
        s[t] += u;
        __syncthreads();
    }
    if (t < NB) boff[t] = s[t] - v;
    if (t == NB - 1) row_ptr[N] = s[t];   // == E
}

__global__ void k_scan3(const int* __restrict__ deg, const int* __restrict__ boff, int* __restrict__ row_ptr) {
    __shared__ int s[256];
    int t = threadIdx.x, i = blockIdx.x * 256 + t;
    int v = (i < N) ? deg[i] : 0;
    s[t] = v;
    __syncthreads();
    for (int off = 1; off < 256; off <<= 1) {
        int u = (t >= off) ? s[t - off] : 0;
        __syncthreads();
        s[t] += u;
        __syncthreads();
    }
    if (i < N) row_ptr[i] = boff[blockIdx.x] + s[t] - v;
}

__global__ void k_fill(const int* __restrict__ src, const int* __restrict__ dst,
                       const float* __restrict__ dis, const int* __restrict__ row_ptr,
                       int* __restrict__ cnt, int* __restrict__ col, float* __restrict__ ew) {
    int e = blockIdx.x * 256 + threadIdx.x;
    if (e < E) {
        int s_ = src[e], d_ = dst[e];
        float w = dis[d_] * dis[s_];
        int p = row_ptr[d_] + atomicAdd(&cnt[d_], 1);
        col[p] = s_;
        ew[p]  = w;
    }
}

// ---------------- mark nodes whose layer-1 aggregation is actually consumed ----------------
__global__ void k_mark(const int* __restrict__ eidx, const int* __restrict__ emask,
                       const int* __restrict__ rowp, const int* __restrict__ col,
                       char* __restrict__ mark) {
    int i = blockIdx.x * 256 + threadIdx.x;   // entity slot
    if (i >= S * EMAX) return;
    if (!emask[i]) return;
    int node = eidx[i];
    int beg = rowp[node], end = rowp[node + 1];
    for (int e = beg; e < end; e++) mark[col[e]] = 1;   // idempotent byte writes
}

// ---------------- convW -> transposed bf16: Bt[layer][n][k] ----------------
__global__ void k_cvtB(const float* __restrict__ W, ushort* __restrict__ Bt) {
    int i = blockIdx.x * 256 + threadIdx.x;
    if (i < 2 * 256 * 256) {
        int L = i >> 16, n = (i >> 8) & 255, k = i & 255;
        Bt[i] = (ushort)bf16rne(W[L * 65536 + k * 256 + n]);
    }
}

// ---------------- MFMA GEMM: Cb[M,256](bf16) = A[M,256] @ Bt^T ----------------
template<bool AF32>
__global__ __launch_bounds__(512) void k_mmb(const void* __restrict__ Av, const ushort* __restrict__ Bt,
                                             ushort* __restrict__ Cb, int M) {
    __shared__ ushort As[128 * 32];
    __shared__ ushort Bs[256 * 32];
    const float*  Af = (const float*)Av;
    const ushort* Ah = (const ushort*)Av;
    int tid = threadIdx.x;
    int lane = tid & 63;
    int wid = tid >> 6, wr = wid >> 2, wc = wid & 3;
    int m0 = blockIdx.x * 128;
    int ra = tid >> 2, ca = tid & 3;   // staging row / 16B-chunk

    f32x4 acc[4][4];
#pragma unroll
    for (int mi = 0; mi < 4; mi++)
#pragma unroll
        for (int ni = 0; ni < 4; ni++) acc[mi][ni] = (f32x4){0.f, 0.f, 0.f, 0.f};

    auto ldA = [&](int kt) -> uint4 {
        uint4 r{0u, 0u, 0u, 0u};
        int grow = m0 + ra;
        if (grow < M) {
            if constexpr (AF32) {
                const float* ap = Af + (size_t)grow * 256 + kt * 32 + ca * 8;
                float4 f0 = *(const float4*)ap;
                float4 f1 = *(const float4*)(ap + 4);
                r.x = pk2(f0.x, f0.y); r.y = pk2(f0.z, f0.w);
                r.z = pk2(f1.x, f1.y); r.w = pk2(f1.z, f1.w);
            } else {
                r = *(const uint4*)(Ah + (size_t)grow * 256 + kt * 32 + ca * 8);
            }
        }
        return r;
    };

    uint4 pa  = ldA(0);
    uint4 pb0 = *(const uint4*)&Bt[(size_t)ra * 256 + ca * 8];
    uint4 pb1 = *(const uint4*)&Bt[(size_t)(ra + 128) * 256 + ca * 8];

    for (int kt = 0; kt < 8; kt++) {
        *(uint4*)&As[ra * 32 + ca * 8] = pa;
        *(uint4*)&Bs[ra * 32 + ca * 8] = pb0;
        *(uint4*)&Bs[(ra + 128) * 32 + ca * 8] = pb1;
        __syncthreads();
        if (kt < 7) {
            pa  = ldA(kt + 1);
            pb0 = *(const uint4*)&Bt[(size_t)ra * 256 + (kt + 1) * 32 + ca * 8];
            pb1 = *(const uint4*)&Bt[(size_t)(ra + 128) * 256 + (kt + 1) * 32 + ca * 8];
        }
        short8 af[4], bf[4];
#pragma unroll
        for (int mi = 0; mi < 4; mi++)
            af[mi] = __builtin_bit_cast(short8,
                *(const uint4*)&As[(wr * 64 + mi * 16 + (lane & 15)) * 32 + (lane >> 4) * 8]);
#pragma unroll
        for (int ni = 0; ni < 4; ni++)
            bf[ni] = __builtin_bit_cast(short8,
                *(const uint4*)&Bs[(wc * 64 + ni * 16 + (lane & 15)) * 32 + (lane >> 4) * 8]);
#pragma unroll
        for (int mi = 0; mi < 4; mi++)
#pragma unroll
            for (int ni = 0; ni < 4; ni++)
                acc[mi][ni] = __builtin_amdgcn_mfma_f32_16x16x32_bf16(af[mi], bf[ni], acc[mi][ni], 0, 0, 0);
        __syncthreads();
    }

    // epilogue: C/D mapping col=lane&15, row=(lane>>4)*4+j  (m89-verified)
#pragma unroll
    for (int mi = 0; mi < 4; mi++)
#pragma unroll
        for (int j = 0; j < 4; j++) {
            int row = m0 + wr * 64 + mi * 16 + (lane >> 4) * 4 + j;
            if (row < M) {
#pragma unroll
                for (int ni = 0; ni < 4; ni++) {
                    int colc = wc * 64 + ni * 16 + (lane & 15);
                    Cb[(size_t)row * 256 + colc] = (ushort)bf16rne(acc[mi][ni][j]);
                }
            }
        }
}

// ---------------- layer-1 aggregation (bf16 gather, bf16 out, masked) ----------------
__global__ __launch_bounds__(256) void k_aggb(const ushort* __restrict__ tb, const int* __restrict__ row_ptr,
                                              const int* __restrict__ col, const float* __restrict__ ew,
                                              const char* __restrict__ mark, ushort* __restrict__ ob) {
    int wid = blockIdx.x * 4 + (threadIdx.x >> 6);
    int lane = threadIdx.x & 63;
    if (wid >= N) return;
    if (!mark[wid]) return;              // wave-uniform skip: output never consumed
    int beg = row_ptr[wid], end = row_ptr[wid + 1];
    float a0 = 0.f, a1 = 0.f, a2 = 0.f, a3 = 0.f;
    int e = beg;
    for (; e + 4 <= end; e += 4) {
        int s0 = col[e], s1 = col[e + 1], s2 = col[e + 2], s3 = col[e + 3];
        float w0 = ew[e], w1 = ew[e + 1], w2 = ew[e + 2], w3 = ew[e + 3];
        ushort4 v0 = *(const ushort4*)&tb[(size_t)s0 * 256 + lane * 4];
        ushort4 v1 = *(const ushort4*)&tb[(size_t)s1 * 256 + lane * 4];
        ushort4 v2 = *(const ushort4*)&tb[(size_t)s2 * 256 + lane * 4];
        ushort4 v3 = *(const ushort4*)&tb[(size_t)s3 * 256 + lane * 4];
        a0 += w0 * bf2f(v0.x) + w1 * bf2f(v1.x) + w2 * bf2f(v2.x) + w3 * bf2f(v3.x);
        a1 += w0 * bf2f(v0.y) + w1 * bf2f(v1.y) + w2 * bf2f(v2.y) + w3 * bf2f(v3.y);
        a2 += w0 * bf2f(v0.z) + w1 * bf2f(v1.z) + w2 * bf2f(v2.z) + w3 * bf2f(v3.z);
        a3 += w0 * bf2f(v0.w) + w1 * bf2f(v1.w) + w2 * bf2f(v2.w) + w3 * bf2f(v3.w);
    }
    for (; e < end; e++) {
        int s0 = col[e];
        float w0 = ew[e];
        ushort4 v0 = *(const ushort4*)&tb[(size_t)s0 * 256 + lane * 4];
        a0 += w0 * bf2f(v0.x);
        a1 += w0 * bf2f(v0.y);
        a2 += w0 * bf2f(v0.z);
        a3 += w0 * bf2f(v0.w);
    }
    a0 = fmaxf(a0, 0.f); a1 = fmaxf(a1, 0.f); a2 = fmaxf(a2, 0.f); a3 = fmaxf(a3, 0.f);
    ushort4 o = {(ushort)bf16rne(a0), (ushort)bf16rne(a1), (ushort)bf16rne(a2), (ushort)bf16rne(a3)};
    *(ushort4*)&ob[(size_t)wid * 256 + lane * 4] = o;
}

// ---------------- fused layer-2 aggregation + sentence entity pooling ----------------
__global__ __launch_bounds__(256) void k_sent3(const ushort* __restrict__ tb, const int* __restrict__ rowp,
                                               const int* __restrict__ col, const float* __restrict__ ew,
                                               const int* __restrict__ eidx, const int* __restrict__ emask,
                                               const float* __restrict__ sW, const float* __restrict__ sb,
                                               float* __restrict__ sf) {
    __shared__ float entS[8][256];
    int s_ = blockIdx.x, tid = threadIdx.x;
#pragma unroll
    for (int e = 0; e < EMAX; e++) {
        int mk = emask[s_ * EMAX + e];
        float acc = 0.f;
        if (mk) {
            int idx = eidx[s_ * EMAX + e];
            int beg = rowp[idx], end = rowp[idx + 1];
            int ed = beg;
            for (; ed + 2 <= end; ed += 2) {
                int n0 = col[ed], n1 = col[ed + 1];       // block-uniform -> scalar loads
                float w0 = ew[ed], w1 = ew[ed + 1];
                acc += w0 * bf2f(tb[(size_t)n0 * 256 + tid])
                     + w1 * bf2f(tb[(size_t)n1 * 256 + tid]);
            }
            if (ed < end) {
                acc += ew[ed] * bf2f(tb[(size_t)col[ed] * 256 + tid]);
            }
        }
        entS[e][tid] = fmaxf(acc, 0.f);   // layer-2 relu; masked slots stay 0
    }
    __syncthreads();
    float b = sb[tid];
    float acc[8];
#pragma unroll
    for (int e = 0; e < EMAX; e++) acc[e] = b;
    for (int k4 = 0; k4 < 64; k4++) {
        float4 w = *(const float4*)&sW[(size_t)tid * 256 + k4 * 4];
#pragma unroll
        for (int e = 0; e < EMAX; e++) {
            float4 v = *(const float4*)&entS[e][k4 * 4];
            acc[e] += w.x * v.x + w.y * v.y + w.z * v.z + w.w * v.w;
        }
    }
    float sum = 0.f, len = 0.f;
#pragma unroll
    for (int e = 0; e < EMAX; e++) {
        int mk = emask[s_ * EMAX + e];
        if (mk) { sum += fmaxf(acc[e], 0.f); len += 1.f; }
    }
    sf[(size_t)s_ * 256 + tid] = sum / (1e-6f + len);
}

// ---------------- input-side LSTM gates (Wih read once per 16 sentences) ----------------
// Xg4[s*1024 + hidx*4 + gate]
__global__ __launch_bounds__(256) void k_xg2(const float* __restrict__ sf, const float* __restrict__ Wih,
                                             const float* __restrict__ bih, const float* __restrict__ bhh,
                                             float* __restrict__ Xg4) {
    __shared__ float sfS[16 * 256];
    int sb = blockIdx.x, y = blockIdx.y, tid = threadIdx.x;
    for (int i = tid; i < 16 * 256; i += 256) sfS[i] = sf[(size_t)(sb * 16) * 256 + i];
    __syncthreads();
    int r = y * 256 + tid;
    float acc[16];
#pragma unroll
    for (int si = 0; si < 16; si++) acc[si] = 0.f;
    for (int k4 = 0; k4 < 64; k4++) {
        float4 w = *(const float4*)&Wih[(size_t)r * 256 + k4 * 4];
#pragma unroll
        for (int si = 0; si < 16; si++) {
            float4 v = *(const float4*)&sfS[si * 256 + k4 * 4];
            acc[si] += w.x * v.x + w.y * v.y + w.z * v.z + w.w * v.w;
        }
    }
    float bb = bih[r] + bhh[r];
#pragma unroll
    for (int si = 0; si < 16; si++)
        Xg4[(size_t)(sb * 16 + si) * 1024 + tid * 4 + y] = acc[si] + bb;
}

// ---------------- W_hh -> packed f16x2, register/LDS/stream layout ----------------
// Thread tid of k_lstm8: q = tid>>8 (col chunk), hidx = tid&255.
// p=0 (VGPR-resident): j<32 -> gate i, j>=32 -> gate f
// p=1: j<32 -> gate g (k-blocks 0-5 LDS, 6-7 streamed), j>=32 -> gate o (streamed)
// Packed dword index = p*65536 + (j>>2)*4096 + tid*4 + (j&3)
__global__ void k_pack(const float* __restrict__ W, uint32_t* __restrict__ Wpk) {
    int idx = blockIdx.x * 256 + threadIdx.x;
    if (idx >= 2 * 64 * 1024) return;
    int p    = idx >> 16;
    int j4   = (idx >> 12) & 15;
    int tid  = (idx >> 2) & 1023;
    int m    = idx & 3;
    int j    = j4 * 4 + m;
    int gate = (p == 0) ? ((j < 32) ? 0 : 1) : ((j < 32) ? 2 : 3);
    int jj   = j & 31;
    int q    = tid >> 8, hidx = tid & 255;
    int row  = gate * 256 + hidx;
    int c0   = q * 64 + jj * 2;
    float a = W[row * 256 + c0], b = W[row * 256 + c0 + 1];
    uint32_t lo = (uint32_t)__half_as_ushort(__float2half(a));
    uint32_t hi = (uint32_t)__half_as_ushort(__float2half(b));
    Wpk[idx] = lo | (hi << 16);
}

// ---------------- sequential LSTM v8: lstm4 skeleton + DS/L2 rebalance ----------------
// lstm4 is DS-issue-bound (~3500 cy/step) with the o-gate L2 stream (2290 cy)
// fully hidden. Move 1/4 of the g-gate weights (k-blocks 6,7) from LDS to the
// L2 stream: DS ~3120 cy, L2 ~2920 cy -> balanced.
__global__ __launch_bounds__(1024, 4) void k_lstm8(const float* __restrict__ Xg4,
                                                   const uint32_t* __restrict__ Wpk,
                                                   const float* __restrict__ nsp,
                                                   float* __restrict__ sol_out) {
    __shared__ uint32_t gW[24576];    // gate g weights, k-blocks 0..5 (96 KB)
    __shared__ uint32_t hqd[128];     // h as 256 f16
    __shared__ float4   gsm4[1024];   // per-thread gate partials (i,f,g,o)
    __shared__ float    nspS[512];
    int tid = threadIdx.x;
    int q = tid >> 8;
    const uint4* Wpk4 = (const uint4*)Wpk;
    uint4* gW4 = (uint4*)gW;

    uint4 wr[16];
#pragma unroll
    for (int j4 = 0; j4 < 16; j4++) wr[j4] = Wpk4[j4 * 1024 + tid];
#pragma unroll
    for (int k = 0; k < 6; k++) gW4[k * 1024 + tid] = Wpk4[16384 + k * 1024 + tid];

    if (tid < 128) hqd[tid] = 0u;
    if (tid < 512) nspS[tid] = (tid < 511) ? nsp[tid] : 0.f;
    float c = 0.f, sol = 0.f;
    __syncthreads();

    for (int t = 0; t < S; t++) {
        float4 xg;
        if (tid < 256) xg = *(const float4*)&Xg4[t * 1024 + tid * 4];
        float pi = 0.f, pf = 0.f, pg = 0.f, po = 0.f;
#pragma unroll
        for (int k = 0; k < 8; k++) {
            uint4 so = Wpk4[16384 + (k + 8) * 1024 + tid];   // gate o, L2 stream
            uint4 sg = (k < 6) ? gW4[k * 1024 + tid]          // gate g, LDS (k<6)
                               : Wpk4[16384 + k * 1024 + tid]; // gate g tail, L2 stream
            uint4 hv = *(const uint4*)&hqd[q * 32 + k * 4];  // wave-uniform broadcast
            pi = fdot2f(wr[k].x, hv.x, pi);
            pi = fdot2f(wr[k].y, hv.y, pi);
            pi = fdot2f(wr[k].z, hv.z, pi);
            pi = fdot2f(wr[k].w, hv.w, pi);
            pf = fdot2f(wr[k + 8].x, hv.x, pf);
            pf = fdot2f(wr[k + 8].y, hv.y, pf);
            pf = fdot2f(wr[k + 8].z, hv.z, pf);
            pf = fdot2f(wr[k + 8].w, hv.w, pf);
            pg = fdot2f(sg.x, hv.x, pg);
            pg = fdot2f(sg.y, hv.y, pg);
            pg = fdot2f(sg.z, hv.z, pg);
            pg = fdot2f(sg.w, hv.w, pg);
            po = fdot2f(so.x, hv.x, po);
            po = fdot2f(so.y, hv.y, po);
            po = fdot2f(so.z, hv.z, po);
            po = fdot2f(so.w, hv.w, po);
        }
        float4 part = {pi, pf, pg, po};
        gsm4[tid] = part;
        __syncthreads();
        if (tid < 256) {
            float gi = xg.x, gf = xg.y, gg = xg.z, go = xg.w;
#pragma unroll
            for (int qq = 0; qq < 4; qq++) {
                float4 v = gsm4[qq * 256 + tid];
                gi += v.x; gf += v.y; gg += v.z; go += v.w;
            }
            float i_ = sigm(gi);
            float f_ = sigm(gf);
            float g_ = tanhfast(gg);
            float o_ = sigm(go);
            c = f_ * c + i_ * g_;
            float h = o_ * tanhfast(c);
            float wgt = ((t > 0) ? nspS[t - 1] : 0.f) + nspS[t];  // nspS[511]==0
            sol += wgt * h;
            ((__half*)hqd)[tid] = __float2half(h);
        }
        __syncthreads();
    }
    if (tid < 256) sol_out[tid] = sol;
}

// ---------------- final head ----------------
__global__ __launch_bounds__(256) void k_final(const float* __restrict__ sol, const float* __restrict__ cls,
                                               const float* __restrict__ redW, const float* __restrict__ redb,
                                               const float* __restrict__ finW, const float* __restrict__ finb,
                                               float* __restrict__ out) {
    __shared__ float clsS[256];
    __shared__ float psum[256];
    int j = threadIdx.x;
    clsS[j] = cls[j];
    __syncthreads();
    float acc = redb[j];
#pragma unroll 8
    for (int k = 0; k < 256; k++) acc += clsS[k] * redW[j * 256 + k];
    float p = sol[j] * finW[j] + acc * finW[256 + j];
    psum[j] = p;
    __syncthreads();
    for (int off = 128; off > 0; off >>= 1) {
        if (j < off) psum[j] += psum[j + off];
        __syncthreads();
    }
    if (j == 0) {
        float o = psum[0] + finb[0];
        o = fmaxf(o, 0.f);
        out[0] = 1.f / (1.f + expf(-o));
    }
}

extern "C" void kernel_launch(void* const* d_in, const int* in_sizes, int n_in,
                              void* d_out, int out_size, void* d_ws, size_t ws_size,
                              hipStream_t stream) {
    const float* x      = (const float*)d_in[0];
    const int*   eidx2  = (const int*)d_in[1];
    const int*   entidx = (const int*)d_in[2];
    const int*   entmsk = (const int*)d_in[3];
    const float* nsp    = (const float*)d_in[4];
    const float* cls    = (const float*)d_in[5];
    const float* convW  = (const float*)d_in[6];
    const float* sentW  = (const float*)d_in[7];
    const float* sentb  = (const float*)d_in[8];
    const float* Wih    = (const float*)d_in[9];
    const float* Whh    = (const float*)d_in[10];
    const float* bih    = (const float*)d_in[11];
    const float* bhh    = (const float*)d_in[12];
    const float* redW   = (const float*)d_in[13];
    const float* redb   = (const float*)d_in[14];
    const float* finW   = (const float*)d_in[15];
    const float* finb   = (const float*)d_in[16];
    const int* src = eidx2;
    const int* dst = eidx2 + E;

    char* w = (char*)d_ws;
    auto alloc = [&](size_t bytes) { char* p = w; w += (bytes + 255) & ~(size_t)255; return p; };
    int*      deg  = (int*)alloc((size_t)N * 4);
    float*    dis  = (float*)alloc((size_t)N * 4);
    int*      rowp = (int*)alloc((size_t)(N + 1) * 4);
    int*      cnt  = (int*)alloc((size_t)N * 4);
    int*      bsum = (int*)alloc((size_t)NB * 4);
    int*      boff = (int*)alloc((size_t)NB * 4);
    int*      col  = (int*)alloc((size_t)E * 4);
    float*    ew   = (float*)alloc((size_t)E * 4);
    ushort*   tb   = (ushort*)alloc((size_t)N * D * 2);   // mm output (bf16)
    ushort*   hb1  = (ushort*)alloc((size_t)N * D * 2);   // layer-1 h (bf16)
    char*     mark = (char*)alloc((size_t)N);
    float*    sf   = (float*)alloc((size_t)S * D * 4);
    float*    Xg   = (float*)alloc((size_t)S * G4 * 4);
    uint32_t* Wpk  = (uint32_t*)alloc((size_t)2 * 64 * 1024 * 4);
    ushort*   Bt   = (ushort*)alloc((size_t)2 * 256 * 256 * 2);
    float*    sol  = (float*)alloc((size_t)H * 4);

    hipMemsetAsync(deg, 0, (size_t)N * 4, stream);
    hipMemsetAsync(cnt, 0, (size_t)N * 4, stream);
    hipMemsetAsync(mark, 0, (size_t)N, stream);

    k_deg<<<(E + 255) / 256, 256, 0, stream>>>(dst, deg);
    k_dis<<<(N + 255) / 256, 256, 0, stream>>>(deg, dis);
    k_scan1<<<NB, 256, 0, stream>>>(deg, bsum);
    k_scan2<<<1, 512, 0, stream>>>(bsum, boff, rowp);
    k_scan3<<<NB, 256, 0, stream>>>(deg, boff, rowp);
    k_fill<<<(E + 255) / 256, 256, 0, stream>>>(src, dst, dis, rowp, cnt, col, ew);
    k_mark<<<(S * EMAX + 255) / 256, 256, 0, stream>>>(entidx, entmsk, rowp, col, mark);
    k_pack<<<(2 * 64 * 1024 + 255) / 256, 256, 0, stream>>>(Whh, Wpk);
    k_cvtB<<<(2 * 256 * 256 + 255) / 256, 256, 0, stream>>>(convW, Bt);

    int mmg = (N + 127) / 128;
    k_mmb<true><<<mmg, 512, 0, stream>>>(x, Bt, tb, N);
    k_aggb<<<(N + 3) / 4, 256, 0, stream>>>(tb, rowp, col, ew, mark, hb1);
    k_mmb<false><<<mmg, 512, 0, stream>>>(hb1, Bt + 65536, tb, N);

    k_sent3<<<S, 256, 0, stream>>>(tb, rowp, col, ew, entidx, entmsk, sentW, sentb, sf);
    k_xg2<<<dim3(32, 4), 256, 0, stream>>>(sf, Wih, bih, bhh, Xg);
    k_lstm8<<<1, 1024, 0, stream>>>(Xg, Wpk, nsp, sol);
    k_final<<<1, 256, 0, stream>>>(sol, cls, redW, redb, finW, finb, (float*)d_out);
}

// Round 11
// 1217.252 us; speedup vs baseline: 1.0372x; 1.0372x over previous
//
#include <hip/hip_runtime.h>
#include <hip/hip_fp16.h>
#include <stdint.h>

// Problem constants (fixed by reference)
constexpr int N    = 100000;
constexpr int D    = 256;
constexpr int E    = 1600000;
constexpr int S    = 512;
constexpr int EMAX = 8;
constexpr int H    = 256;
constexpr int G4   = 4 * H;           // 1024 gate rows
constexpr int NB   = (N + 255) / 256; // 391 scan blocks

typedef _Float16 h2_t __attribute__((ext_vector_type(2)));
typedef __attribute__((ext_vector_type(8))) short short8;
typedef __attribute__((ext_vector_type(4))) float f32x4;

static __device__ __forceinline__ float fdot2f(uint32_t a, uint32_t b, float c) {
#if __has_builtin(__builtin_amdgcn_fdot2)
    return __builtin_amdgcn_fdot2(__builtin_bit_cast(h2_t, a), __builtin_bit_cast(h2_t, b), c, false);
#else
    __half2 ha = __builtin_bit_cast(__half2, a), hb = __builtin_bit_cast(__half2, b);
    float2 fa = __half22float2(ha), fb = __half22float2(hb);
    return c + fa.x * fb.x + fa.y * fb.y;
#endif
}

static __device__ __forceinline__ uint32_t bf16rne(float f) {
    uint32_t u = __builtin_bit_cast(uint32_t, f);
    return (u + 0x7FFFu + ((u >> 16) & 1u)) >> 16;
}
static __device__ __forceinline__ uint32_t pk2(float a, float b) {
    return bf16rne(a) | (bf16rne(b) << 16);
}
static __device__ __forceinline__ float bf2f(uint32_t hi16) {
    return __builtin_bit_cast(float, hi16 << 16);
}
static __device__ __forceinline__ uint32_t pkh2(float a, float b) {
    __half2 h = __halves2half2(__float2half(a), __float2half(b));
    return __builtin_bit_cast(uint32_t, h);
}
static __device__ __forceinline__ float2 uph2(uint32_t v) {
    return __half22float2(__builtin_bit_cast(__half2, v));
}
static __device__ __forceinline__ float sigm(float x) { return 1.f / (1.f + __expf(-x)); }
static __device__ __forceinline__ float tanhfast(float x) {
    float e = __expf(-2.f * x);
    return 2.f / (1.f + e) - 1.f;
}

// ---------------- degree / norm ----------------
__global__ void k_deg(const int* __restrict__ dst, int* __restrict__ deg) {
    int e = blockIdx.x * 256 + threadIdx.x;
    if (e < E) atomicAdd(&deg[dst[e]], 1);
}

__global__ void k_dis(const int* __restrict__ deg, float* __restrict__ dis) {
    int n = blockIdx.x * 256 + threadIdx.x;
    if (n < N) {
        int d = deg[n];
        dis[n] = (d > 0) ? (1.0f / sqrtf((float)d)) : 0.0f;
    }
}

// ---------------- CSR build (scan over deg) ----------------
__global__ void k_scan1(const int* __restrict__ deg, int* __restrict__ bsum) {
    __shared__ int s[256];
    int i = blockIdx.x * 256 + threadIdx.x;
    s[threadIdx.x] = (i < N) ? deg[i] : 0;
    __syncthreads();
    for (int off = 128; off > 0; off >>= 1) {
        if (threadIdx.x < off) s[threadIdx.x] += s[threadIdx.x + off];
        __syncthreads();
    }
    if (threadIdx.x == 0) bsum[blockIdx.x] = s[0];
}

__global__ void k_scan2(const int* __restrict__ bsum, int* __restrict__ boff, int* __restrict__ row_ptr) {
    __shared__ int s[512];
    int t = threadIdx.x;
    int v = (t < NB) ? bsum[t] : 0;
    s[t] = v;
    __syncthreads();
    for (int off = 1; off < 512; off <<= 1) {
        int u = (t >= off) ? s[t - off] : 0;
        __syncthreads();
        s[t] += u;
        __syncthreads();
    }
    if (t < NB) boff[t] = s[t] - v;
    if (t == NB - 1) row_ptr[N] = s[t];   // == E
}

__global__ void k_scan3(const int* __restrict__ deg, const int* __restrict__ boff, int* __restrict__ row_ptr) {
    __shared__ int s[256];
    int t = threadIdx.x, i = blockIdx.x * 256 + t;
    int v = (i < N) ? deg[i] : 0;
    s[t] = v;
    __syncthreads();
    for (int off = 1; off < 256; off <<= 1) {
        int u = (t >= off) ? s[t - off] : 0;
        __syncthreads();
        s[t] += u;
        __syncthreads();
    }
    if (i < N) row_ptr[i] = boff[blockIdx.x] + s[t] - v;
}

__global__ void k_fill(const int* __restrict__ src, const int* __restrict__ dst,
                       const float* __restrict__ dis, const int* __restrict__ row_ptr,
                       int* __restrict__ cnt, int* __restrict__ col, float* __restrict__ ew) {
    int e = blockIdx.x * 256 + threadIdx.x;
    if (e < E) {
        int s_ = src[e], d_ = dst[e];
        float w = dis[d_] * dis[s_];
        int p = row_ptr[d_] + atomicAdd(&cnt[d_], 1);
        col[p] = s_;
        ew[p]  = w;
    }
}

// ---------------- mark nodes whose layer-1 aggregation is actually consumed ----------------
__global__ void k_mark(const int* __restrict__ eidx, const int* __restrict__ emask,
                       const int* __restrict__ rowp, const int* __restrict__ col,
                       char* __restrict__ mark) {
    int i = blockIdx.x * 256 + threadIdx.x;   // entity slot
    if (i >= S * EMAX) return;
    if (!emask[i]) return;
    int node = eidx[i];
    int beg = rowp[node], end = rowp[node + 1];
    for (int e = beg; e < end; e++) mark[col[e]] = 1;   // idempotent byte writes
}

// ---------------- convW -> transposed bf16: Bt[layer][n][k] ----------------
__global__ void k_cvtB(const float* __restrict__ W, ushort* __restrict__ Bt) {
    int i = blockIdx.x * 256 + threadIdx.x;
    if (i < 2 * 256 * 256) {
        int L = i >> 16, n = (i >> 8) & 255, k = i & 255;
        Bt[i] = (ushort)bf16rne(W[L * 65536 + k * 256 + n]);
    }
}

// ---------------- MFMA GEMM: Cb[M,256](bf16) = A[M,256] @ Bt^T ----------------
template<bool AF32>
__global__ __launch_bounds__(512) void k_mmb(const void* __restrict__ Av, const ushort* __restrict__ Bt,
                                             ushort* __restrict__ Cb, int M) {
    __shared__ ushort As[128 * 32];
    __shared__ ushort Bs[256 * 32];
    const float*  Af = (const float*)Av;
    const ushort* Ah = (const ushort*)Av;
    int tid = threadIdx.x;
    int lane = tid & 63;
    int wid = tid >> 6, wr = wid >> 2, wc = wid & 3;
    int m0 = blockIdx.x * 128;
    int ra = tid >> 2, ca = tid & 3;   // staging row / 16B-chunk

    f32x4 acc[4][4];
#pragma unroll
    for (int mi = 0; mi < 4; mi++)
#pragma unroll
        for (int ni = 0; ni < 4; ni++) acc[mi][ni] = (f32x4){0.f, 0.f, 0.f, 0.f};

    auto ldA = [&](int kt) -> uint4 {
        uint4 r{0u, 0u, 0u, 0u};
        int grow = m0 + ra;
        if (grow < M) {
            if constexpr (AF32) {
                const float* ap = Af + (size_t)grow * 256 + kt * 32 + ca * 8;
                float4 f0 = *(const float4*)ap;
                float4 f1 = *(const float4*)(ap + 4);
                r.x = pk2(f0.x, f0.y); r.y = pk2(f0.z, f0.w);
                r.z = pk2(f1.x, f1.y); r.w = pk2(f1.z, f1.w);
            } else {
                r = *(const uint4*)(Ah + (size_t)grow * 256 + kt * 32 + ca * 8);
            }
        }
        return r;
    };

    uint4 pa  = ldA(0);
    uint4 pb0 = *(const uint4*)&Bt[(size_t)ra * 256 + ca * 8];
    uint4 pb1 = *(const uint4*)&Bt[(size_t)(ra + 128) * 256 + ca * 8];

    for (int kt = 0; kt < 8; kt++) {
        *(uint4*)&As[ra * 32 + ca * 8] = pa;
        *(uint4*)&Bs[ra * 32 + ca * 8] = pb0;
        *(uint4*)&Bs[(ra + 128) * 32 + ca * 8] = pb1;
        __syncthreads();
        if (kt < 7) {
            pa  = ldA(kt + 1);
            pb0 = *(const uint4*)&Bt[(size_t)ra * 256 + (kt + 1) * 32 + ca * 8];
            pb1 = *(const uint4*)&Bt[(size_t)(ra + 128) * 256 + (kt + 1) * 32 + ca * 8];
        }
        short8 af[4], bf[4];
#pragma unroll
        for (int mi = 0; mi < 4; mi++)
            af[mi] = __builtin_bit_cast(short8,
                *(const uint4*)&As[(wr * 64 + mi * 16 + (lane & 15)) * 32 + (lane >> 4) * 8]);
#pragma unroll
        for (int ni = 0; ni < 4; ni++)
            bf[ni] = __builtin_bit_cast(short8,
                *(const uint4*)&Bs[(wc * 64 + ni * 16 + (lane & 15)) * 32 + (lane >> 4) * 8]);
#pragma unroll
        for (int mi = 0; mi < 4; mi++)
#pragma unroll
            for (int ni = 0; ni < 4; ni++)
                acc[mi][ni] = __builtin_amdgcn_mfma_f32_16x16x32_bf16(af[mi], bf[ni], acc[mi][ni], 0, 0, 0);
        __syncthreads();
    }

    // epilogue: C/D mapping col=lane&15, row=(lane>>4)*4+j  (m89-verified)
#pragma unroll
    for (int mi = 0; mi < 4; mi++)
#pragma unroll
        for (int j = 0; j < 4; j++) {
            int row = m0 + wr * 64 + mi * 16 + (lane >> 4) * 4 + j;
            if (row < M) {
#pragma unroll
                for (int ni = 0; ni < 4; ni++) {
                    int colc = wc * 64 + ni * 16 + (lane & 15);
                    Cb[(size_t)row * 256 + colc] = (ushort)bf16rne(acc[mi][ni][j]);
                }
            }
        }
}

// ---------------- layer-1 aggregation (bf16 gather, bf16 out, masked) ----------------
__global__ __launch_bounds__(256) void k_aggb(const ushort* __restrict__ tb, const int* __restrict__ row_ptr,
                                              const int* __restrict__ col, const float* __restrict__ ew,
                                              const char* __restrict__ mark, ushort* __restrict__ ob) {
    int wid = blockIdx.x * 4 + (threadIdx.x >> 6);
    int lane = threadIdx.x & 63;
    if (wid >= N) return;
    if (!mark[wid]) return;              // wave-uniform skip: output never consumed
    int beg = row_ptr[wid], end = row_ptr[wid + 1];
    float a0 = 0.f, a1 = 0.f, a2 = 0.f, a3 = 0.f;
    int e = beg;
    for (; e + 4 <= end; e += 4) {
        int s0 = col[e], s1 = col[e + 1], s2 = col[e + 2], s3 = col[e + 3];
        float w0 = ew[e], w1 = ew[e + 1], w2 = ew[e + 2], w3 = ew[e + 3];
        ushort4 v0 = *(const ushort4*)&tb[(size_t)s0 * 256 + lane * 4];
        ushort4 v1 = *(const ushort4*)&tb[(size_t)s1 * 256 + lane * 4];
        ushort4 v2 = *(const ushort4*)&tb[(size_t)s2 * 256 + lane * 4];
        ushort4 v3 = *(const ushort4*)&tb[(size_t)s3 * 256 + lane * 4];
        a0 += w0 * bf2f(v0.x) + w1 * bf2f(v1.x) + w2 * bf2f(v2.x) + w3 * bf2f(v3.x);
        a1 += w0 * bf2f(v0.y) + w1 * bf2f(v1.y) + w2 * bf2f(v2.y) + w3 * bf2f(v3.y);
        a2 += w0 * bf2f(v0.z) + w1 * bf2f(v1.z) + w2 * bf2f(v2.z) + w3 * bf2f(v3.z);
        a3 += w0 * bf2f(v0.w) + w1 * bf2f(v1.w) + w2 * bf2f(v2.w) + w3 * bf2f(v3.w);
    }
    for (; e < end; e++) {
        int s0 = col[e];
        float w0 = ew[e];
        ushort4 v0 = *(const ushort4*)&tb[(size_t)s0 * 256 + lane * 4];
        a0 += w0 * bf2f(v0.x);
        a1 += w0 * bf2f(v0.y);
        a2 += w0 * bf2f(v0.z);
        a3 += w0 * bf2f(v0.w);
    }
    a0 = fmaxf(a0, 0.f); a1 = fmaxf(a1, 0.f); a2 = fmaxf(a2, 0.f); a3 = fmaxf(a3, 0.f);
    ushort4 o = {(ushort)bf16rne(a0), (ushort)bf16rne(a1), (ushort)bf16rne(a2), (ushort)bf16rne(a3)};
    *(ushort4*)&ob[(size_t)wid * 256 + lane * 4] = o;
}

// ---------------- fused layer-2 aggregation + sentence entity pooling ----------------
__global__ __launch_bounds__(256) void k_sent3(const ushort* __restrict__ tb, const int* __restrict__ rowp,
                                               const int* __restrict__ col, const float* __restrict__ ew,
                                               const int* __restrict__ eidx, const int* __restrict__ emask,
                                               const float* __restrict__ sW, const float* __restrict__ sb,
                                               float* __restrict__ sf) {
    __shared__ float entS[8][256];
    int s_ = blockIdx.x, tid = threadIdx.x;
#pragma unroll
    for (int e = 0; e < EMAX; e++) {
        int mk = emask[s_ * EMAX + e];
        float acc = 0.f;
        if (mk) {
            int idx = eidx[s_ * EMAX + e];
            int beg = rowp[idx], end = rowp[idx + 1];
            int ed = beg;
            for (; ed + 2 <= end; ed += 2) {
                int n0 = col[ed], n1 = col[ed + 1];       // block-uniform -> scalar loads
                float w0 = ew[ed], w1 = ew[ed + 1];
                acc += w0 * bf2f(tb[(size_t)n0 * 256 + tid])
                     + w1 * bf2f(tb[(size_t)n1 * 256 + tid]);
            }
            if (ed < end) {
                acc += ew[ed] * bf2f(tb[(size_t)col[ed] * 256 + tid]);
            }
        }
        entS[e][tid] = fmaxf(acc, 0.f);   // layer-2 relu; masked slots stay 0
    }
    __syncthreads();
    float b = sb[tid];
    float acc[8];
#pragma unroll
    for (int e = 0; e < EMAX; e++) acc[e] = b;
    for (int k4 = 0; k4 < 64; k4++) {
        float4 w = *(const float4*)&sW[(size_t)tid * 256 + k4 * 4];
#pragma unroll
        for (int e = 0; e < EMAX; e++) {
            float4 v = *(const float4*)&entS[e][k4 * 4];
            acc[e] += w.x * v.x + w.y * v.y + w.z * v.z + w.w * v.w;
        }
    }
    float sum = 0.f, len = 0.f;
#pragma unroll
    for (int e = 0; e < EMAX; e++) {
        int mk = emask[s_ * EMAX + e];
        if (mk) { sum += fmaxf(acc[e], 0.f); len += 1.f; }
    }
    sf[(size_t)s_ * 256 + tid] = sum / (1e-6f + len);
}

// ---------------- input-side LSTM gates (Wih read once per 16 sentences) ----------------
// Xg4[s*1024 + hidx*4 + gate]
__global__ __launch_bounds__(256) void k_xg2(const float* __restrict__ sf, const float* __restrict__ Wih,
                                             const float* __restrict__ bih, const float* __restrict__ bhh,
                                             float* __restrict__ Xg4) {
    __shared__ float sfS[16 * 256];
    int sb = blockIdx.x, y = blockIdx.y, tid = threadIdx.x;
    for (int i = tid; i < 16 * 256; i += 256) sfS[i] = sf[(size_t)(sb * 16) * 256 + i];
    __syncthreads();
    int r = y * 256 + tid;
    float acc[16];
#pragma unroll
    for (int si = 0; si < 16; si++) acc[si] = 0.f;
    for (int k4 = 0; k4 < 64; k4++) {
        float4 w = *(const float4*)&Wih[(size_t)r * 256 + k4 * 4];
#pragma unroll
        for (int si = 0; si < 16; si++) {
            float4 v = *(const float4*)&sfS[si * 256 + k4 * 4];
            acc[si] += w.x * v.x + w.y * v.y + w.z * v.z + w.w * v.w;
        }
    }
    float bb = bih[r] + bhh[r];
#pragma unroll
    for (int si = 0; si < 16; si++)
        Xg4[(size_t)(sb * 16 + si) * 1024 + tid * 4 + y] = acc[si] + bb;
}

// ---------------- W_hh -> packed f16x2, register/LDS/stream layout ----------------
// Thread tid of k_lstm9: q = tid>>8 (col chunk), hidx = tid&255.
// p=0 (VGPR-resident): j<32 -> gate i, j>=32 -> gate f
// p=1: j<32 -> gate g (LDS-resident), j>=32 -> gate o (streamed from L2)
// Packed dword index = p*65536 + (j>>2)*4096 + tid*4 + (j&3)
__global__ void k_pack(const float* __restrict__ W, uint32_t* __restrict__ Wpk) {
    int idx = blockIdx.x * 256 + threadIdx.x;
    if (idx >= 2 * 64 * 1024) return;
    int p    = idx >> 16;
    int j4   = (idx >> 12) & 15;
    int tid  = (idx >> 2) & 1023;
    int m    = idx & 3;
    int j    = j4 * 4 + m;
    int gate = (p == 0) ? ((j < 32) ? 0 : 1) : ((j < 32) ? 2 : 3);
    int jj   = j & 31;
    int q    = tid >> 8, hidx = tid & 255;
    int row  = gate * 256 + hidx;
    int c0   = q * 64 + jj * 2;
    float a = W[row * 256 + c0], b = W[row * 256 + c0 + 1];
    uint32_t lo = (uint32_t)__half_as_ushort(__float2half(a));
    uint32_t hi = (uint32_t)__half_as_ushort(__float2half(b));
    Wpk[idx] = lo | (hi << 16);
}

// ---------------- sequential LSTM v9: lstm4 skeleton, lean partial-reduce ----------------
// lstm4's residency split is optimal (VGPR i,f / LDS g / L2 o — proven by 4
// head-to-heads). Only change: q==0 threads (== the update threads) keep their
// partials in registers; q=1..3 write f16x4-packed partials (b64), update reads
// 3x b64. gsm round-trip: 32 b128 wave-ops -> 24 b64 (~190 cy/step saved).
__global__ __launch_bounds__(1024, 4) void k_lstm9(const float* __restrict__ Xg4,
                                                   const uint32_t* __restrict__ Wpk,
                                                   const float* __restrict__ nsp,
                                                   float* __restrict__ sol_out) {
    __shared__ uint32_t gW[32768];    // gate g weights (128 KB)
    __shared__ uint32_t hqd[128];     // h as 256 f16
    __shared__ uint2    gsm2[768];    // packed partials, q=1..3: [(q-1)*256+hidx]
    __shared__ float    nspS[512];
    int tid = threadIdx.x;
    int q = tid >> 8;
    const uint4* Wpk4 = (const uint4*)Wpk;
    uint4* gW4 = (uint4*)gW;

    uint4 wr[16];
#pragma unroll
    for (int j4 = 0; j4 < 16; j4++) wr[j4] = Wpk4[j4 * 1024 + tid];
#pragma unroll
    for (int k = 0; k < 8; k++) gW4[k * 1024 + tid] = Wpk4[16384 + k * 1024 + tid];

    if (tid < 128) hqd[tid] = 0u;
    if (tid < 512) nspS[tid] = (tid < 511) ? nsp[tid] : 0.f;
    float c = 0.f, sol = 0.f;
    __syncthreads();

    for (int t = 0; t < S; t++) {
        float4 xg;
        if (tid < 256) xg = *(const float4*)&Xg4[t * 1024 + tid * 4];
        float pi = 0.f, pf = 0.f, pg = 0.f, po = 0.f;
#pragma unroll
        for (int k = 0; k < 8; k++) {
            uint4 so = Wpk4[16384 + (k + 8) * 1024 + tid];   // gate o, L2 stream
            uint4 sg = gW4[k * 1024 + tid];                  // gate g, LDS
            uint4 hv = *(const uint4*)&hqd[q * 32 + k * 4];  // wave-uniform broadcast
            pi = fdot2f(wr[k].x, hv.x, pi);
            pi = fdot2f(wr[k].y, hv.y, pi);
            pi = fdot2f(wr[k].z, hv.z, pi);
            pi = fdot2f(wr[k].w, hv.w, pi);
            pf = fdot2f(wr[k + 8].x, hv.x, pf);
            pf = fdot2f(wr[k + 8].y, hv.y, pf);
            pf = fdot2f(wr[k + 8].z, hv.z, pf);
            pf = fdot2f(wr[k + 8].w, hv.w, pf);
            pg = fdot2f(sg.x, hv.x, pg);
            pg = fdot2f(sg.y, hv.y, pg);
            pg = fdot2f(sg.z, hv.z, pg);
            pg = fdot2f(sg.w, hv.w, pg);
            po = fdot2f(so.x, hv.x, po);
            po = fdot2f(so.y, hv.y, po);
            po = fdot2f(so.z, hv.z, po);
            po = fdot2f(so.w, hv.w, po);
        }
        if (q > 0) {
            uint2 pk_ = {pkh2(pi, pf), pkh2(pg, po)};
            gsm2[(q - 1) * 256 + (tid & 255)] = pk_;
        }
        __syncthreads();
        if (tid < 256) {
            float gi = xg.x + pi, gf = xg.y + pf, gg = xg.z + pg, go = xg.w + po;
#pragma unroll
            for (int qq = 0; qq < 3; qq++) {
                uint2 v = gsm2[qq * 256 + tid];
                float2 a = uph2(v.x), b = uph2(v.y);
                gi += a.x; gf += a.y; gg += b.x; go += b.y;
            }
            float i_ = sigm(gi);
            float f_ = sigm(gf);
            float g_ = tanhfast(gg);
            float o_ = sigm(go);
            c = f_ * c + i_ * g_;
            float h = o_ * tanhfast(c);
            float wgt = ((t > 0) ? nspS[t - 1] : 0.f) + nspS[t];  // nspS[511]==0
            sol += wgt * h;
            ((__half*)hqd)[tid] = __float2half(h);
        }
        __syncthreads();
    }
    if (tid < 256) sol_out[tid] = sol;
}

// ---------------- final head ----------------
__global__ __launch_bounds__(256) void k_final(const float* __restrict__ sol, const float* __restrict__ cls,
                                               const float* __restrict__ redW, const float* __restrict__ redb,
                                               const float* __restrict__ finW, const float* __restrict__ finb,
                                               float* __restrict__ out) {
    __shared__ float clsS[256];
    __shared__ float psum[256];
    int j = threadIdx.x;
    clsS[j] = cls[j];
    __syncthreads();
    float acc = redb[j];
#pragma unroll 8
    for (int k = 0; k < 256; k++) acc += clsS[k] * redW[j * 256 + k];
    float p = sol[j] * finW[j] + acc * finW[256 + j];
    psum[j] = p;
    __syncthreads();
    for (int off = 128; off > 0; off >>= 1) {
        if (j < off) psum[j] += psum[j + off];
        __syncthreads();
    }
    if (j == 0) {
        float o = psum[0] + finb[0];
        o = fmaxf(o, 0.f);
        out[0] = 1.f / (1.f + expf(-o));
    }
}

extern "C" void kernel_launch(void* const* d_in, const int* in_sizes, int n_in,
                              void* d_out, int out_size, void* d_ws, size_t ws_size,
                              hipStream_t stream) {
    const float* x      = (const float*)d_in[0];
    const int*   eidx2  = (const int*)d_in[1];
    const int*   entidx = (const int*)d_in[2];
    const int*   entmsk = (const int*)d_in[3];
    const float* nsp    = (const float*)d_in[4];
    const float* cls    = (const float*)d_in[5];
    const float* convW  = (const float*)d_in[6];
    const float* sentW  = (const float*)d_in[7];
    const float* sentb  = (const float*)d_in[8];
    const float* Wih    = (const float*)d_in[9];
    const float* Whh    = (const float*)d_in[10];
    const float* bih    = (const float*)d_in[11];
    const float* bhh    = (const float*)d_in[12];
    const float* redW   = (const float*)d_in[13];
    const float* redb   = (const float*)d_in[14];
    const float* finW   = (const float*)d_in[15];
    const float* finb   = (const float*)d_in[16];
    const int* src = eidx2;
    const int* dst = eidx2 + E;

    char* w = (char*)d_ws;
    auto alloc = [&](size_t bytes) { char* p = w; w += (bytes + 255) & ~(size_t)255; return p; };
    int*      deg  = (int*)alloc((size_t)N * 4);
    float*    dis  = (float*)alloc((size_t)N * 4);
    int*      rowp = (int*)alloc((size_t)(N + 1) * 4);
    int*      cnt  = (int*)alloc((size_t)N * 4);
    int*      bsum = (int*)alloc((size_t)NB * 4);
    int*      boff = (int*)alloc((size_t)NB * 4);
    int*      col  = (int*)alloc((size_t)E * 4);
    float*    ew   = (float*)alloc((size_t)E * 4);
    ushort*   tb   = (ushort*)alloc((size_t)N * D * 2);   // mm output (bf16)
    ushort*   hb1  = (ushort*)alloc((size_t)N * D * 2);   // layer-1 h (bf16)
    char*     mark = (char*)alloc((size_t)N);
    float*    sf   = (float*)alloc((size_t)S * D * 4);
    float*    Xg   = (float*)alloc((size_t)S * G4 * 4);
    uint32_t* Wpk  = (uint32_t*)alloc((size_t)2 * 64 * 1024 * 4);
    ushort*   Bt   = (ushort*)alloc((size_t)2 * 256 * 256 * 2);
    float*    sol  = (float*)alloc((size_t)H * 4);

    hipMemsetAsync(deg, 0, (size_t)N * 4, stream);
    hipMemsetAsync(cnt, 0, (size_t)N * 4, stream);
    hipMemsetAsync(mark, 0, (size_t)N, stream);

    k_deg<<<(E + 255) / 256, 256, 0, stream>>>(dst, deg);
    k_dis<<<(N + 255) / 256, 256, 0, stream>>>(deg, dis);
    k_scan1<<<NB, 256, 0, stream>>>(deg, bsum);
    k_scan2<<<1, 512, 0, stream>>>(bsum, boff, rowp);
    k_scan3<<<NB, 256, 0, stream>>>(deg, boff, rowp);
    k_fill<<<(E + 255) / 256, 256, 0, stream>>>(src, dst, dis, rowp, cnt, col, ew);
    k_mark<<<(S * EMAX + 255) / 256, 256, 0, stream>>>(entidx, entmsk, rowp, col, mark);
    k_pack<<<(2 * 64 * 1024 + 255) / 256, 256, 0, stream>>>(Whh, Wpk);
    k_cvtB<<<(2 * 256 * 256 + 255) / 256, 256, 0, stream>>>(convW, Bt);

    int mmg = (N + 127) / 128;
    k_mmb<true><<<mmg, 512, 0, stream>>>(x, Bt, tb, N);
    k_aggb<<<(N + 3) / 4, 256, 0, stream>>>(tb, rowp, col, ew, mark, hb1);
    k_mmb<false><<<mmg, 512, 0, stream>>>(hb1, Bt + 65536, tb, N);

    k_sent3<<<S, 256, 0, stream>>>(tb, rowp, col, ew, entidx, entmsk, sentW, sentb, sf);
    k_xg2<<<dim3(32, 4), 256, 0, stream>>>(sf, Wih, bih, bhh, Xg);
    k_lstm9<<<1, 1024, 0, stream>>>(Xg, Wpk, nsp, sol);
    k_final<<<1, 256, 0, stream>>>(sol, cls, redW, redb, finW, finb, (float*)d_out);
}

// Round 12
// 1164.098 us; speedup vs baseline: 1.0846x; 1.0457x over previous
//
#include <hip/hip_runtime.h>
#include <hip/hip_fp16.h>
#include <stdint.h>

// Problem constants (fixed by reference)
constexpr int N    = 100000;
constexpr int D    = 256;
constexpr int E    = 1600000;
constexpr int S    = 512;
constexpr int EMAX = 8;
constexpr int H    = 256;
constexpr int G4   = 4 * H;           // 1024 gate rows
constexpr int NB   = (N + 255) / 256; // 391 scan blocks

typedef _Float16 h2_t __attribute__((ext_vector_type(2)));
typedef __attribute__((ext_vector_type(8))) short short8;
typedef __attribute__((ext_vector_type(4))) float f32x4;

static __device__ __forceinline__ float fdot2f(uint32_t a, uint32_t b, float c) {
#if __has_builtin(__builtin_amdgcn_fdot2)
    return __builtin_amdgcn_fdot2(__builtin_bit_cast(h2_t, a), __builtin_bit_cast(h2_t, b), c, false);
#else
    __half2 ha = __builtin_bit_cast(__half2, a), hb = __builtin_bit_cast(__half2, b);
    float2 fa = __half22float2(ha), fb = __half22float2(hb);
    return c + fa.x * fb.x + fa.y * fb.y;
#endif
}

static __device__ __forceinline__ uint32_t bf16rne(float f) {
    uint32_t u = __builtin_bit_cast(uint32_t, f);
    return (u + 0x7FFFu + ((u >> 16) & 1u)) >> 16;
}
static __device__ __forceinline__ uint32_t pk2(float a, float b) {
    return bf16rne(a) | (bf16rne(b) << 16);
}
static __device__ __forceinline__ float bf2f(uint32_t hi16) {
    return __builtin_bit_cast(float, hi16 << 16);
}
static __device__ __forceinline__ float sigm(float x) { return 1.f / (1.f + __expf(-x)); }
static __device__ __forceinline__ float tanhfast(float x) {
    float e = __expf(-2.f * x);
    return 2.f / (1.f + e) - 1.f;
}

// ---------------- degree / norm ----------------
__global__ void k_deg(const int* __restrict__ dst, int* __restrict__ deg) {
    int e = blockIdx.x * 256 + threadIdx.x;
    if (e < E) atomicAdd(&deg[dst[e]], 1);
}

__global__ void k_dis(const int* __restrict__ deg, float* __restrict__ dis) {
    int n = blockIdx.x * 256 + threadIdx.x;
    if (n < N) {
        int d = deg[n];
        dis[n] = (d > 0) ? (1.0f / sqrtf((float)d)) : 0.0f;
    }
}

// ---------------- CSR build (scan over deg) ----------------
__global__ void k_scan1(const int* __restrict__ deg, int* __restrict__ bsum) {
    __shared__ int s[256];
    int i = blockIdx.x * 256 + threadIdx.x;
    s[threadIdx.x] = (i < N) ? deg[i] : 0;
    __syncthreads();
    for (int off = 128; off > 0; off >>= 1) {
        if (threadIdx.x < off) s[threadIdx.x] += s[threadIdx.x + off];
        __syncthreads();
    }
    if (threadIdx.x == 0) bsum[blockIdx.x] = s[0];
}

__global__ void k_scan2(const int* __restrict__ bsum, int* __restrict__ boff, int* __restrict__ row_ptr) {
    __shared__ int s[512];
    int t = threadIdx.x;
    int v = (t < NB) ? bsum[t] : 0;
    s[t] = v;
    __syncthreads();
    for (int off = 1; off < 512; off <<= 1) {
        int u = (t >= off) ? s[t - off] : 0;
        __syncthreads();
        s[t] += u;
        __syncthreads();
    }
    if (t < NB) boff[t] = s[t] - v;
    if (t == NB - 1) row_ptr[N] = s[t];   // == E
}

__global__ void k_scan3(const int* __restrict__ deg, const int* __restrict__ boff, int* __restrict__ row_ptr) {
    __shared__ int s[256];
    int t = threadIdx.x, i = blockIdx.x * 256 + t;
    int v = (i < N) ? deg[i] : 0;
    s[t] = v;
    __syncthreads();
    for (int off = 1; off < 256; off <<= 1) {
        int u = (t >= off) ? s[t - off] : 0;
        __syncthreads();
        s[t] += u;
        __syncthreads();
    }
    if (i < N) row_ptr[i] = boff[blockIdx.x] + s[t] - v;
}

__global__ void k_fill(const int* __restrict__ src, const int* __restrict__ dst,
                       const float* __restrict__ dis, const int* __restrict__ row_ptr,
                       int* __restrict__ cnt, int* __restrict__ col, float* __restrict__ ew) {
    int e = blockIdx.x * 256 + threadIdx.x;
    if (e < E) {
        int s_ = src[e], d_ = dst[e];
        float w = dis[d_] * dis[s_];
        int p = row_ptr[d_] + atomicAdd(&cnt[d_], 1);
        col[p] = s_;
        ew[p]  = w;
    }
}

// ---------------- mark nodes whose layer-1 aggregation is actually consumed ----------------
__global__ void k_mark(const int* __restrict__ eidx, const int* __restrict__ emask,
                       const int* __restrict__ rowp, const int* __restrict__ col,
                       char* __restrict__ mark) {
    int i = blockIdx.x * 256 + threadIdx.x;   // entity slot
    if (i >= S * EMAX) return;
    if (!emask[i]) return;
    int node = eidx[i];
    int beg = rowp[node], end = rowp[node + 1];
    for (int e = beg; e < end; e++) mark[col[e]] = 1;   // idempotent byte writes
}

// ---------------- convW -> transposed bf16: Bt[layer][n][k] ----------------
__global__ void k_cvtB(const float* __restrict__ W, ushort* __restrict__ Bt) {
    int i = blockIdx.x * 256 + threadIdx.x;
    if (i < 2 * 256 * 256) {
        int L = i >> 16, n = (i >> 8) & 255, k = i & 255;
        Bt[i] = (ushort)bf16rne(W[L * 65536 + k * 256 + n]);
    }
}

// ---------------- MFMA GEMM: Cb[M,256](bf16) = A[M,256] @ Bt^T ----------------
template<bool AF32>
__global__ __launch_bounds__(512) void k_mmb(const void* __restrict__ Av, const ushort* __restrict__ Bt,
                                             ushort* __restrict__ Cb, int M) {
    __shared__ ushort As[128 * 32];
    __shared__ ushort Bs[256 * 32];
    const float*  Af = (const float*)Av;
    const ushort* Ah = (const ushort*)Av;
    int tid = threadIdx.x;
    int lane = tid & 63;
    int wid = tid >> 6, wr = wid >> 2, wc = wid & 3;
    int m0 = blockIdx.x * 128;
    int ra = tid >> 2, ca = tid & 3;   // staging row / 16B-chunk

    f32x4 acc[4][4];
#pragma unroll
    for (int mi = 0; mi < 4; mi++)
#pragma unroll
        for (int ni = 0; ni < 4; ni++) acc[mi][ni] = (f32x4){0.f, 0.f, 0.f, 0.f};

    auto ldA = [&](int kt) -> uint4 {
        uint4 r{0u, 0u, 0u, 0u};
        int grow = m0 + ra;
        if (grow < M) {
            if constexpr (AF32) {
                const float* ap = Af + (size_t)grow * 256 + kt * 32 + ca * 8;
                float4 f0 = *(const float4*)ap;
                float4 f1 = *(const float4*)(ap + 4);
                r.x = pk2(f0.x, f0.y); r.y = pk2(f0.z, f0.w);
                r.z = pk2(f1.x, f1.y); r.w = pk2(f1.z, f1.w);
            } else {
                r = *(const uint4*)(Ah + (size_t)grow * 256 + kt * 32 + ca * 8);
            }
        }
        return r;
    };

    uint4 pa  = ldA(0);
    uint4 pb0 = *(const uint4*)&Bt[(size_t)ra * 256 + ca * 8];
    uint4 pb1 = *(const uint4*)&Bt[(size_t)(ra + 128) * 256 + ca * 8];

    for (int kt = 0; kt < 8; kt++) {
        *(uint4*)&As[ra * 32 + ca * 8] = pa;
        *(uint4*)&Bs[ra * 32 + ca * 8] = pb0;
        *(uint4*)&Bs[(ra + 128) * 32 + ca * 8] = pb1;
        __syncthreads();
        if (kt < 7) {
            pa  = ldA(kt + 1);
            pb0 = *(const uint4*)&Bt[(size_t)ra * 256 + (kt + 1) * 32 + ca * 8];
            pb1 = *(const uint4*)&Bt[(size_t)(ra + 128) * 256 + (kt + 1) * 32 + ca * 8];
        }
        short8 af[4], bf[4];
#pragma unroll
        for (int mi = 0; mi < 4; mi++)
            af[mi] = __builtin_bit_cast(short8,
                *(const uint4*)&As[(wr * 64 + mi * 16 + (lane & 15)) * 32 + (lane >> 4) * 8]);
#pragma unroll
        for (int ni = 0; ni < 4; ni++)
            bf[ni] = __builtin_bit_cast(short8,
                *(const uint4*)&Bs[(wc * 64 + ni * 16 + (lane & 15)) * 32 + (lane >> 4) * 8]);
#pragma unroll
        for (int mi = 0; mi < 4; mi++)
#pragma unroll
            for (int ni = 0; ni < 4; ni++)
                acc[mi][ni] = __builtin_amdgcn_mfma_f32_16x16x32_bf16(af[mi], bf[ni], acc[mi][ni], 0, 0, 0);
        __syncthreads();
    }

    // epilogue: C/D mapping col=lane&15, row=(lane>>4)*4+j  (m89-verified)
#pragma unroll
    for (int mi = 0; mi < 4; mi++)
#pragma unroll
        for (int j = 0; j < 4; j++) {
            int row = m0 + wr * 64 + mi * 16 + (lane >> 4) * 4 + j;
            if (row < M) {
#pragma unroll
                for (int ni = 0; ni < 4; ni++) {
                    int colc = wc * 64 + ni * 16 + (lane & 15);
                    Cb[(size_t)row * 256 + colc] = (ushort)bf16rne(acc[mi][ni][j]);
                }
            }
        }
}

// ---------------- layer-1 aggregation (bf16 gather, bf16 out, masked) ----------------
__global__ __launch_bounds__(256) void k_aggb(const ushort* __restrict__ tb, const int* __restrict__ row_ptr,
                                              const int* __restrict__ col, const float* __restrict__ ew,
                                              const char* __restrict__ mark, ushort* __restrict__ ob) {
    int wid = blockIdx.x * 4 + (threadIdx.x >> 6);
    int lane = threadIdx.x & 63;
    if (wid >= N) return;
    if (!mark[wid]) return;              // wave-uniform skip: output never consumed
    int beg = row_ptr[wid], end = row_ptr[wid + 1];
    float a0 = 0.f, a1 = 0.f, a2 = 0.f, a3 = 0.f;
    int e = beg;
    for (; e + 4 <= end; e += 4) {
        int s0 = col[e], s1 = col[e + 1], s2 = col[e + 2], s3 = col[e + 3];
        float w0 = ew[e], w1 = ew[e + 1], w2 = ew[e + 2], w3 = ew[e + 3];
        ushort4 v0 = *(const ushort4*)&tb[(size_t)s0 * 256 + lane * 4];
        ushort4 v1 = *(const ushort4*)&tb[(size_t)s1 * 256 + lane * 4];
        ushort4 v2 = *(const ushort4*)&tb[(size_t)s2 * 256 + lane * 4];
        ushort4 v3 = *(const ushort4*)&tb[(size_t)s3 * 256 + lane * 4];
        a0 += w0 * bf2f(v0.x) + w1 * bf2f(v1.x) + w2 * bf2f(v2.x) + w3 * bf2f(v3.x);
        a1 += w0 * bf2f(v0.y) + w1 * bf2f(v1.y) + w2 * bf2f(v2.y) + w3 * bf2f(v3.y);
        a2 += w0 * bf2f(v0.z) + w1 * bf2f(v1.z) + w2 * bf2f(v2.z) + w3 * bf2f(v3.z);
        a3 += w0 * bf2f(v0.w) + w1 * bf2f(v1.w) + w2 * bf2f(v2.w) + w3 * bf2f(v3.w);
    }
    for (; e < end; e++) {
        int s0 = col[e];
        float w0 = ew[e];
        ushort4 v0 = *(const ushort4*)&tb[(size_t)s0 * 256 + lane * 4];
        a0 += w0 * bf2f(v0.x);
        a1 += w0 * bf2f(v0.y);
        a2 += w0 * bf2f(v0.z);
        a3 += w0 * bf2f(v0.w);
    }
    a0 = fmaxf(a0, 0.f); a1 = fmaxf(a1, 0.f); a2 = fmaxf(a2, 0.f); a3 = fmaxf(a3, 0.f);
    ushort4 o = {(ushort)bf16rne(a0), (ushort)bf16rne(a1), (ushort)bf16rne(a2), (ushort)bf16rne(a3)};
    *(ushort4*)&ob[(size_t)wid * 256 + lane * 4] = o;
}

// ---------------- fused layer-2 aggregation + sentence entity pooling ----------------
__global__ __launch_bounds__(256) void k_sent3(const ushort* __restrict__ tb, const int* __restrict__ rowp,
                                               const int* __restrict__ col, const float* __restrict__ ew,
                                               const int* __restrict__ eidx, const int* __restrict__ emask,
                                               const float* __restrict__ sW, const float* __restrict__ sb,
                                               float* __restrict__ sf) {
    __shared__ float entS[8][256];
    int s_ = blockIdx.x, tid = threadIdx.x;
#pragma unroll
    for (int e = 0; e < EMAX; e++) {
        int mk = emask[s_ * EMAX + e];
        float acc = 0.f;
        if (mk) {
            int idx = eidx[s_ * EMAX + e];
            int beg = rowp[idx], end = rowp[idx + 1];
            int ed = beg;
            for (; ed + 2 <= end; ed += 2) {
                int n0 = col[ed], n1 = col[ed + 1];       // block-uniform -> scalar loads
                float w0 = ew[ed], w1 = ew[ed + 1];
                acc += w0 * bf2f(tb[(size_t)n0 * 256 + tid])
                     + w1 * bf2f(tb[(size_t)n1 * 256 + tid]);
            }
            if (ed < end) {
                acc += ew[ed] * bf2f(tb[(size_t)col[ed] * 256 + tid]);
            }
        }
        entS[e][tid] = fmaxf(acc, 0.f);   // layer-2 relu; masked slots stay 0
    }
    __syncthreads();
    float b = sb[tid];
    float acc[8];
#pragma unroll
    for (int e = 0; e < EMAX; e++) acc[e] = b;
    for (int k4 = 0; k4 < 64; k4++) {
        float4 w = *(const float4*)&sW[(size_t)tid * 256 + k4 * 4];
#pragma unroll
        for (int e = 0; e < EMAX; e++) {
            float4 v = *(const float4*)&entS[e][k4 * 4];
            acc[e] += w.x * v.x + w.y * v.y + w.z * v.z + w.w * v.w;
        }
    }
    float sum = 0.f, len = 0.f;
#pragma unroll
    for (int e = 0; e < EMAX; e++) {
        int mk = emask[s_ * EMAX + e];
        if (mk) { sum += fmaxf(acc[e], 0.f); len += 1.f; }
    }
    sf[(size_t)s_ * 256 + tid] = sum / (1e-6f + len);
}

// ---------------- input-side LSTM gates (Wih read once per 16 sentences) ----------------
// Xg4[s*1024 + hidx*4 + gate]
__global__ __launch_bounds__(256) void k_xg2(const float* __restrict__ sf, const float* __restrict__ Wih,
                                             const float* __restrict__ bih, const float* __restrict__ bhh,
                                             float* __restrict__ Xg4) {
    __shared__ float sfS[16 * 256];
    int sb = blockIdx.x, y = blockIdx.y, tid = threadIdx.x;
    for (int i = tid; i < 16 * 256; i += 256) sfS[i] = sf[(size_t)(sb * 16) * 256 + i];
    __syncthreads();
    int r = y * 256 + tid;
    float acc[16];
#pragma unroll
    for (int si = 0; si < 16; si++) acc[si] = 0.f;
    for (int k4 = 0; k4 < 64; k4++) {
        float4 w = *(const float4*)&Wih[(size_t)r * 256 + k4 * 4];
#pragma unroll
        for (int si = 0; si < 16; si++) {
            float4 v = *(const float4*)&sfS[si * 256 + k4 * 4];
            acc[si] += w.x * v.x + w.y * v.y + w.z * v.z + w.w * v.w;
        }
    }
    float bb = bih[r] + bhh[r];
#pragma unroll
    for (int si = 0; si < 16; si++)
        Xg4[(size_t)(sb * 16 + si) * 1024 + tid * 4 + y] = acc[si] + bb;
}

// ---------------- W_hh -> packed f16x2, register/LDS/stream layout ----------------
// Thread tid of k_lstm4: q = tid>>8 (col chunk), hidx = tid&255.
// p=0 (VGPR-resident): j<32 -> gate i, j>=32 -> gate f
// p=1: j<32 -> gate g (LDS-resident), j>=32 -> gate o (streamed from L2)
// Packed dword index = p*65536 + (j>>2)*4096 + tid*4 + (j&3)
__global__ void k_pack(const float* __restrict__ W, uint32_t* __restrict__ Wpk) {
    int idx = blockIdx.x * 256 + threadIdx.x;
    if (idx >= 2 * 64 * 1024) return;
    int p    = idx >> 16;
    int j4   = (idx >> 12) & 15;
    int tid  = (idx >> 2) & 1023;
    int m    = idx & 3;
    int j    = j4 * 4 + m;
    int gate = (p == 0) ? ((j < 32) ? 0 : 1) : ((j < 32) ? 2 : 3);
    int jj   = j & 31;
    int q    = tid >> 8, hidx = tid & 255;
    int row  = gate * 256 + hidx;
    int c0   = q * 64 + jj * 2;
    float a = W[row * 256 + c0], b = W[row * 256 + c0 + 1];
    uint32_t lo = (uint32_t)__half_as_ushort(__float2half(a));
    uint32_t hi = (uint32_t)__half_as_ushort(__float2half(b));
    Wpk[idx] = lo | (hi << 16);
}

// ---------------- sequential LSTM v4 (proven 785-790 us configuration, FINAL) ----------------
// Residency split VGPR(i,f)/LDS(g)/L2-stream(o) is the empirical optimum:
// five restructurings (all-VGPR, quad-split+shfl, DPP+dbuf, DS/L2 rebalance,
// packed partial reduce) all regressed. DS-issue ~3500 cy/step is the floor.
__global__ __launch_bounds__(1024, 4) void k_lstm4(const float* __restrict__ Xg4,
                                                   const uint32_t* __restrict__ Wpk,
                                                   const float* __restrict__ nsp,
                                                   float* __restrict__ sol_out) {
    __shared__ uint32_t gW[32768];    // gate g weights (128 KB)
    __shared__ uint32_t hqd[128];     // h as 256 f16
    __shared__ float4   gsm4[1024];   // per-thread gate partials (i,f,g,o)
    __shared__ float    nspS[512];
    int tid = threadIdx.x;
    int q = tid >> 8;
    const uint4* Wpk4 = (const uint4*)Wpk;
    uint4* gW4 = (uint4*)gW;

    uint4 wr[16];
#pragma unroll
    for (int j4 = 0; j4 < 16; j4++) wr[j4] = Wpk4[j4 * 1024 + tid];
#pragma unroll
    for (int k = 0; k < 8; k++) gW4[k * 1024 + tid] = Wpk4[16384 + k * 1024 + tid];

    if (tid < 128) hqd[tid] = 0u;
    if (tid < 512) nspS[tid] = (tid < 511) ? nsp[tid] : 0.f;
    float c = 0.f, sol = 0.f;
    __syncthreads();

    for (int t = 0; t < S; t++) {
        float4 xg;
        if (tid < 256) xg = *(const float4*)&Xg4[t * 1024 + tid * 4];
        float pi = 0.f, pf = 0.f, pg = 0.f, po = 0.f;
#pragma unroll
        for (int k = 0; k < 8; k++) {
            uint4 so = Wpk4[16384 + (k + 8) * 1024 + tid];   // gate o, L2 stream
            uint4 sg = gW4[k * 1024 + tid];                  // gate g, LDS
            uint4 hv = *(const uint4*)&hqd[q * 32 + k * 4];  // wave-uniform broadcast
            pi = fdot2f(wr[k].x, hv.x, pi);
            pi = fdot2f(wr[k].y, hv.y, pi);
            pi = fdot2f(wr[k].z, hv.z, pi);
            pi = fdot2f(wr[k].w, hv.w, pi);
            pf = fdot2f(wr[k + 8].x, hv.x, pf);
            pf = fdot2f(wr[k + 8].y, hv.y, pf);
            pf = fdot2f(wr[k + 8].z, hv.z, pf);
            pf = fdot2f(wr[k + 8].w, hv.w, pf);
            pg = fdot2f(sg.x, hv.x, pg);
            pg = fdot2f(sg.y, hv.y, pg);
            pg = fdot2f(sg.z, hv.z, pg);
            pg = fdot2f(sg.w, hv.w, pg);
            po = fdot2f(so.x, hv.x, po);
            po = fdot2f(so.y, hv.y, po);
            po = fdot2f(so.z, hv.z, po);
            po = fdot2f(so.w, hv.w, po);
        }
        float4 part = {pi, pf, pg, po};
        gsm4[tid] = part;
        __syncthreads();
        if (tid < 256) {
            float gi = xg.x, gf = xg.y, gg = xg.z, go = xg.w;
#pragma unroll
            for (int qq = 0; qq < 4; qq++) {
                float4 v = gsm4[qq * 256 + tid];
                gi += v.x; gf += v.y; gg += v.z; go += v.w;
            }
            float i_ = sigm(gi);
            float f_ = sigm(gf);
            float g_ = tanhfast(gg);
            float o_ = sigm(go);
            c = f_ * c + i_ * g_;
            float h = o_ * tanhfast(c);
            float wgt = ((t > 0) ? nspS[t - 1] : 0.f) + nspS[t];  // nspS[511]==0
            sol += wgt * h;
            ((__half*)hqd)[tid] = __float2half(h);
        }
        __syncthreads();
    }
    if (tid < 256) sol_out[tid] = sol;
}

// ---------------- final head ----------------
__global__ __launch_bounds__(256) void k_final(const float* __restrict__ sol, const float* __restrict__ cls,
                                               const float* __restrict__ redW, const float* __restrict__ redb,
                                               const float* __restrict__ finW, const float* __restrict__ finb,
                                               float* __restrict__ out) {
    __shared__ float clsS[256];
    __shared__ float psum[256];
    int j = threadIdx.x;
    clsS[j] = cls[j];
    __syncthreads();
    float acc = redb[j];
#pragma unroll 8
    for (int k = 0; k < 256; k++) acc += clsS[k] * redW[j * 256 + k];
    float p = sol[j] * finW[j] + acc * finW[256 + j];
    psum[j] = p;
    __syncthreads();
    for (int off = 128; off > 0; off >>= 1) {
        if (j < off) psum[j] += psum[j + off];
        __syncthreads();
    }
    if (j == 0) {
        float o = psum[0] + finb[0];
        o = fmaxf(o, 0.f);
        out[0] = 1.f / (1.f + expf(-o));
    }
}

extern "C" void kernel_launch(void* const* d_in, const int* in_sizes, int n_in,
                              void* d_out, int out_size, void* d_ws, size_t ws_size,
                              hipStream_t stream) {
    const float* x      = (const float*)d_in[0];
    const int*   eidx2  = (const int*)d_in[1];
    const int*   entidx = (const int*)d_in[2];
    const int*   entmsk = (const int*)d_in[3];
    const float* nsp    = (const float*)d_in[4];
    const float* cls    = (const float*)d_in[5];
    const float* convW  = (const float*)d_in[6];
    const float* sentW  = (const float*)d_in[7];
    const float* sentb  = (const float*)d_in[8];
    const float* Wih    = (const float*)d_in[9];
    const float* Whh    = (const float*)d_in[10];
    const float* bih    = (const float*)d_in[11];
    const float* bhh    = (const float*)d_in[12];
    const float* redW   = (const float*)d_in[13];
    const float* redb   = (const float*)d_in[14];
    const float* finW   = (const float*)d_in[15];
    const float* finb   = (const float*)d_in[16];
    const int* src = eidx2;
    const int* dst = eidx2 + E;

    char* w = (char*)d_ws;
    auto alloc = [&](size_t bytes) { char* p = w; w += (bytes + 255) & ~(size_t)255; return p; };
    int*      deg  = (int*)alloc((size_t)N * 4);
    float*    dis  = (float*)alloc((size_t)N * 4);
    int*      rowp = (int*)alloc((size_t)(N + 1) * 4);
    int*      cnt  = (int*)alloc((size_t)N * 4);
    int*      bsum = (int*)alloc((size_t)NB * 4);
    int*      boff = (int*)alloc((size_t)NB * 4);
    int*      col  = (int*)alloc((size_t)E * 4);
    float*    ew   = (float*)alloc((size_t)E * 4);
    ushort*   tb   = (ushort*)alloc((size_t)N * D * 2);   // mm output (bf16)
    ushort*   hb1  = (ushort*)alloc((size_t)N * D * 2);   // layer-1 h (bf16)
    char*     mark = (char*)alloc((size_t)N);
    float*    sf   = (float*)alloc((size_t)S * D * 4);
    float*    Xg   = (float*)alloc((size_t)S * G4 * 4);
    uint32_t* Wpk  = (uint32_t*)alloc((size_t)2 * 64 * 1024 * 4);
    ushort*   Bt   = (ushort*)alloc((size_t)2 * 256 * 256 * 2);
    float*    sol  = (float*)alloc((size_t)H * 4);

    hipMemsetAsync(deg, 0, (size_t)N * 4, stream);
    hipMemsetAsync(cnt, 0, (size_t)N * 4, stream);
    hipMemsetAsync(mark, 0, (size_t)N, stream);

    k_deg<<<(E + 255) / 256, 256, 0, stream>>>(dst, deg);
    k_dis<<<(N + 255) / 256, 256, 0, stream>>>(deg, dis);
    k_scan1<<<NB, 256, 0, stream>>>(deg, bsum);
    k_scan2<<<1, 512, 0, stream>>>(bsum, boff, rowp);
    k_scan3<<<NB, 256, 0, stream>>>(deg, boff, rowp);
    k_fill<<<(E + 255) / 256, 256, 0, stream>>>(src, dst, dis, rowp, cnt, col, ew);
    k_mark<<<(S * EMAX + 255) / 256, 256, 0, stream>>>(entidx, entmsk, rowp, col, mark);
    k_pack<<<(2 * 64 * 1024 + 255) / 256, 256, 0, stream>>>(Whh, Wpk);
    k_cvtB<<<(2 * 256 * 256 + 255) / 256, 256, 0, stream>>>(convW, Bt);

    int mmg = (N + 127) / 128;
    k_mmb<true><<<mmg, 512, 0, stream>>>(x, Bt, tb, N);
    k_aggb<<<(N + 3) / 4, 256, 0, stream>>>(tb, rowp, col, ew, mark, hb1);
    k_mmb<false><<<mmg, 512, 0, stream>>>(hb1, Bt + 65536, tb, N);

    k_sent3<<<S, 256, 0, stream>>>(tb, rowp, col, ew, entidx, entmsk, sentW, sentb, sf);
    k_xg2<<<dim3(32, 4), 256, 0, stream>>>(sf, Wih, bih, bhh, Xg);
    k_lstm4<<<1, 1024, 0, stream>>>(Xg, Wpk, nsp, sol);
    k_final<<<1, 256, 0, stream>>>(sol, cls, redW, redb, finW, finb, (float*)d_out);
}